// Round 1
// 294.418 us; speedup vs baseline: 1.0676x; 1.0676x over previous
//
#include <hip/hip_runtime.h>

// Guided filter r=3 (7x7 box, zero-pad /49), fused streaming kernel. R7.
// R6 was register-over-subscribed (~190 live floats vs 152 VGPR -> unified-file
// spills -> 1-2 waves/SIMD, Occupancy ~9%). R7 flips both separable box
// filters to VERTICAL-FIRST: rolling vertical colsums need history only of
// the leaving RAW row (float4 ring, 32 regs) and leaving AB row (48 regs),
// instead of 7-deep history of all 14 derived horizontal sums (112 regs).
// Horizontal 7-taps now run over per-column colsum rows staged in LDS
// (depth-4 buffers, produced+consumed within one half-step, 2 barriers per
// 4 rows -- same cadence as R6). I at the output row is re-read from the
// raw ring (lag 6), eliminating the Iq prefetch loads entirely.
//
// Thread = image column. Block = 128 threads = 128 input columns
// (116 output cols). Block sweeps 76 rows of a 64-row segment
// (r = 0..75, image row y = Y0-6+r, output row o = y-6, ab row yc = y-3).
// LDS = 4*134*(16+16+16+8) = 30016 B -> 5 blocks/CU; target 3 waves/SIMD.

#define TPB   128
#define OUTW  116
#define SEGH  64
#define HW    1024
#define GW    134          // TPB + 6 guard cells for taps
#define EPSF  1e-6f
#define INV49 (1.0f/49.0f)

struct GFState {
    // raw ring: rows r-8..r-1 of (I,p0,p1,p2); slot = r&7
    float4 rr[8];
    // ab ring: ab rows produced at r-8..r-1; slot = r&7
    float ra0[8], rb0[8], ra1[8], rb1[8], ra2[8], rb2[8];
    // stage-1 vertical colsums (I, I*I, p, I*p) over raw rows y-6..y
    float sI, sII, sp0, sp1, sp2, sq0, sq1, sq2;
    // stage-2 vertical colsums over ab rows yc-6..yc
    float t6a0, t6b0, t6a1, t6b1, t6a2, t6b2;
    // prefetched raw rows for this half-step
    float4 cur[4];
};

template<int JB>
__device__ __forceinline__ void halfStep(
    GFState& S, int j0, int Yb, int x_in, bool xok, int xc, int tid,
    const float* __restrict__ Ip, const float* __restrict__ P0,
    const float* __restrict__ P1, const float* __restrict__ P2,
    float* __restrict__ Q0, float* __restrict__ Q1, float* __restrict__ Q2,
    float4 (*cs8A)[GW], float4 (*cs8B)[GW],
    float4 (*cs6A)[GW], float2 (*cs6B)[GW],
    bool dostore, bool dopref)
{
    // I at this half-step's output rows o = r-6: still in the raw ring
    // (slot (r-6)&7 = (JB+u+2)&7). Read BEFORE W8 evicts (W8 overwrites
    // slots (JB..JB+3)&7, which include (JB+u+2)&7 for u>=... all of them).
    float Io[4];
    #pragma unroll
    for (int u = 0; u < 4; ++u) Io[u] = S.rr[(JB+u+2)&7].x;

    // ---- W8: stage-1 vertical rolling colsums for rows r = j0..j0+3 -> LDS
    #pragma unroll
    for (int u = 0; u < 4; ++u) {
        const float4 c = S.cur[u];
        const float4 o = S.rr[(JB+u+1)&7];      // raw row r-7 (leaving)
        S.sI  += c.x - o.x;
        S.sII += c.x*c.x - o.x*o.x;
        S.sp0 += c.y - o.y;  S.sq0 += c.x*c.y - o.x*o.y;
        S.sp1 += c.z - o.z;  S.sq1 += c.x*c.z - o.x*o.z;
        S.sp2 += c.w - o.w;  S.sq2 += c.x*c.w - o.x*o.w;
        S.rr[(JB+u)&7] = c;
        cs8A[(JB+u)&3][tid+3] = make_float4(S.sI,  S.sII, S.sp0, S.sp1);
        cs8B[(JB+u)&3][tid+3] = make_float4(S.sp2, S.sq0, S.sq1, S.sq2);
    }
    // ---- barrier 1: cs8 writes visible (also protects prev half-step's
    // cs6 reads from this half-step's W6 writes below).
    __syncthreads();

    // ---- R8: horizontal 7-tap on cs8 -> ab row yc = y-3 -> stage-2
    //          vertical rolling colsums -> W6 to LDS
    #pragma unroll
    for (int u = 0; u < 4; ++u) {
        const int ls = (JB+u)&3;
        float4 A = make_float4(0.f,0.f,0.f,0.f);
        float4 B = make_float4(0.f,0.f,0.f,0.f);
        #pragma unroll
        for (int d = 0; d < 7; ++d) {
            float4 a = cs8A[ls][tid+d];
            float4 b = cs8B[ls][tid+d];
            A.x += a.x; A.y += a.y; A.z += a.z; A.w += a.w;
            B.x += b.x; B.y += b.y; B.z += b.z; B.w += b.w;
        }
        const int  yc   = Yb + j0 + u - 3;
        const bool abok = xok && ((unsigned)yc < HW);
        const float mi  = A.x*INV49, mii = A.y*INV49;
        const float rv  = __builtin_amdgcn_rcpf(mii - mi*mi + EPSF);
        float a0,b0,a1,b1,a2,b2, mp, mq, a, b;
        mp = A.z*INV49; mq = B.y*INV49;
        a = (mq - mi*mp)*rv; b = fmaf(-a, mi, mp);
        a0 = abok ? a : 0.f; b0 = abok ? b : 0.f;
        mp = A.w*INV49; mq = B.z*INV49;
        a = (mq - mi*mp)*rv; b = fmaf(-a, mi, mp);
        a1 = abok ? a : 0.f; b1 = abok ? b : 0.f;
        mp = B.x*INV49; mq = B.w*INV49;
        a = (mq - mi*mp)*rv; b = fmaf(-a, mi, mp);
        a2 = abok ? a : 0.f; b2 = abok ? b : 0.f;

        const int as = (JB+u)&7, al = (JB+u+1)&7;   // ab row r-7 leaves
        S.t6a0 += a0 - S.ra0[al]; S.ra0[as] = a0;
        S.t6b0 += b0 - S.rb0[al]; S.rb0[as] = b0;
        S.t6a1 += a1 - S.ra1[al]; S.ra1[as] = a1;
        S.t6b1 += b1 - S.rb1[al]; S.rb1[as] = b1;
        S.t6a2 += a2 - S.ra2[al]; S.ra2[as] = a2;
        S.t6b2 += b2 - S.rb2[al]; S.rb2[as] = b2;
        cs6A[ls][tid+3] = make_float4(S.t6a0, S.t6b0, S.t6a1, S.t6b1);
        cs6B[ls][tid+3] = make_float2(S.t6a2, S.t6b2);
    }
    // ---- barrier 2: cs6 writes visible (also protects this half-step's
    // cs8 reads from next half-step's W8 writes).
    __syncthreads();

    // ---- prefetch raw rows r = j0+4..j0+7 (consumed at next W8; latency
    // hidden under R6 taps + next W8 address math)
    if (dopref) {
        #pragma unroll
        for (int u = 0; u < 4; ++u) {
            const int y  = Yb + j0 + 4 + u;
            const bool ok = xok && ((unsigned)y < HW);
            const int yy = min(max(y, 0), HW-1);
            const size_t off = (size_t)yy*HW + xc;
            float v0 = Ip[off], v1 = P0[off], v2 = P1[off], v3 = P2[off];
            float4 v;
            v.x = ok ? v0 : 0.f; v.y = ok ? v1 : 0.f;
            v.z = ok ? v2 : 0.f; v.w = ok ? v3 : 0.f;
            S.cur[u] = v;
        }
    }

    // ---- R6: horizontal 7-tap on cs6 -> output rows o = r-6
    if (dostore) {
        const bool sok = (tid >= 6) && (tid < 122) && (x_in < HW);
        #pragma unroll
        for (int u = 0; u < 4; ++u) {
            const int ls = (JB+u)&3;
            float4 A6 = make_float4(0.f,0.f,0.f,0.f);
            float2 B6 = make_float2(0.f,0.f);
            #pragma unroll
            for (int d = 0; d < 7; ++d) {
                float4 a = cs6A[ls][tid+d];
                float2 b = cs6B[ls][tid+d];
                A6.x += a.x; A6.y += a.y; A6.z += a.z; A6.w += a.w;
                B6.x += b.x; B6.y += b.y;
            }
            const int o = Yb + j0 + u - 6;
            const size_t ooff = (size_t)o*HW + x_in;
            float q;
            q = fmaf(A6.x*INV49, Io[u], A6.y*INV49);
            q = fminf(fmaxf(q, 0.f), 1.f); if (sok) Q0[ooff] = q;
            q = fmaf(A6.z*INV49, Io[u], A6.w*INV49);
            q = fminf(fmaxf(q, 0.f), 1.f); if (sok) Q1[ooff] = q;
            q = fmaf(B6.x*INV49, Io[u], B6.y*INV49);
            q = fminf(fmaxf(q, 0.f), 1.f); if (sok) Q2[ooff] = q;
        }
    }
}

__global__ __launch_bounds__(TPB, 3) void gf_kernel(
    const float* __restrict__ I, const float* __restrict__ P,
    float* __restrict__ Q)
{
    __shared__ float4 cs8A[4][GW];   // 8576 B: sI,sII,sp0,sp1
    __shared__ float4 cs8B[4][GW];   // 8576 B: sp2,sq0,sq1,sq2
    __shared__ float4 cs6A[4][GW];   // 8576 B: t6a0,t6b0,t6a1,t6b1
    __shared__ float2 cs6B[4][GW];   // 4288 B: t6a2,t6b2   -> 30016 B total

    const int s   = blockIdx.x;      // x-stripe (9)
    const int seg = blockIdx.y;      // y-segment (16)
    const int b   = blockIdx.z;      // batch (8)
    const int tid = threadIdx.x;

    const int X0   = s*OUTW - 6;
    const int Yb   = seg*SEGH - 6;   // image row of sweep r=0
    const int x_in = X0 + tid;
    const bool xok = (unsigned)x_in < HW;
    const int  xc  = min(max(x_in, 0), HW-1);

    const float* Ip = I + (size_t)b*HW*HW;
    const float* P0 = P + ((size_t)b*3 + 0)*HW*HW;
    const float* P1 = P + ((size_t)b*3 + 1)*HW*HW;
    const float* P2 = P + ((size_t)b*3 + 2)*HW*HW;
    float* Q0 = Q + ((size_t)b*3 + 0)*HW*HW;
    float* Q1 = Q + ((size_t)b*3 + 1)*HW*HW;
    float* Q2 = Q + ((size_t)b*3 + 2)*HW*HW;

    // Zero-init LDS once: interior cells are rewritten every half-step, but
    // the 2x3 guard columns per slot are read by edge threads and must be
    // finite (edge-thread results are never stored, but keep them clean).
    {
        float4* zA = (float4*)cs8A;
        float4* zB = (float4*)cs8B;
        float4* zC = (float4*)cs6A;
        float2* zD = (float2*)cs6B;
        const float4 z4 = make_float4(0.f,0.f,0.f,0.f);
        const float2 z2 = make_float2(0.f,0.f);
        for (int i = tid; i < 4*GW; i += TPB) {
            zA[i] = z4; zB[i] = z4; zC[i] = z4; zD[i] = z2;
        }
    }

    GFState S;
    S.sI=S.sII=S.sp0=S.sp1=S.sp2=S.sq0=S.sq1=S.sq2=0.f;
    S.t6a0=S.t6b0=S.t6a1=S.t6b1=S.t6a2=S.t6b2=0.f;
    #pragma unroll
    for (int i = 0; i < 8; ++i) {
        S.rr[i] = make_float4(0.f,0.f,0.f,0.f);
        S.ra0[i]=S.rb0[i]=S.ra1[i]=S.rb1[i]=S.ra2[i]=S.rb2[i]=0.f;
    }
    // preload raw rows r = 0..3
    #pragma unroll
    for (int u = 0; u < 4; ++u) {
        const int y = Yb + u;
        const bool ok = xok && ((unsigned)y < HW);
        const int yy = min(max(y, 0), HW-1);
        const size_t off = (size_t)yy*HW + xc;
        float v0 = Ip[off], v1 = P0[off], v2 = P1[off], v3 = P2[off];
        float4 v;
        v.x = ok ? v0 : 0.f; v.y = ok ? v1 : 0.f;
        v.z = ok ? v2 : 0.f; v.w = ok ? v3 : 0.f;
        S.cur[u] = v;
    }

    __syncthreads();   // LDS zero-init visible before first taps

    // 19 half-steps: r = 0..75 (output rows o = r-12+Y0 valid for r>=12)
    for (int m = 0; m < 9; ++m) {
        const int j0 = m*8;
        halfStep<0>(S, j0,   Yb, x_in, xok, xc, tid, Ip, P0, P1, P2,
                    Q0, Q1, Q2, cs8A, cs8B, cs6A, cs6B,
                    (j0   >= 12), true);
        halfStep<4>(S, j0+4, Yb, x_in, xok, xc, tid, Ip, P0, P1, P2,
                    Q0, Q1, Q2, cs8A, cs8B, cs6A, cs6B,
                    (j0+4 >= 12), true);
    }
    halfStep<0>(S, 72, Yb, x_in, xok, xc, tid, Ip, P0, P1, P2,
                Q0, Q1, Q2, cs8A, cs8B, cs6A, cs6B,
                true, false);
}

extern "C" void kernel_launch(void* const* d_in, const int* in_sizes, int n_in,
                              void* d_out, int out_size, void* d_ws, size_t ws_size,
                              hipStream_t stream) {
    const float* I = (const float*)d_in[0];
    const float* P = (const float*)d_in[1];
    // d_in[2] = radius (always 3; hardcoded)
    float* Q = (float*)d_out;

    dim3 grid(9, 16, 8);   // x-stripes, y-segments, batch
    gf_kernel<<<grid, TPB, 0, stream>>>(I, P, Q);
}

// Round 2
// 285.825 us; speedup vs baseline: 1.0997x; 1.0301x over previous
//
#include <hip/hip_runtime.h>

// Guided filter r=3 (7x7 box, zero-pad /49), fused streaming kernel. R8.
// R7 (vertical-first, LDS colsum staging) fixed the register-state blowup
// but __launch_bounds__(128,3) capped the allocator at ~168 VGPRs and it
// responded by spilling the rings to SCRATCH: VGPR_Count=84 (< the ~150
// live floats), WRITE_SIZE 270MB vs 101MB of outputs, FETCH +30MB.
// R8 = R7 with __launch_bounds__(128,2): cap 256 VGPRs. Occupancy is
// LDS-limited at 5 blocks/CU (30KB/block) either way, so the relaxed bound
// costs nothing and eliminates scratch traffic entirely.
//
// Thread = image column. Block = 128 threads = 128 input columns
// (116 output cols). Block sweeps 76 rows of a 64-row segment
// (r = 0..75, image row y = Yb+r, output row o = y-6, ab row yc = y-3).
// Vertical box sums: rolling register colsums (raw ring depth 8 float4,
// ab ring depth 8 x6). Horizontal 7-taps: LDS colsum rows, depth-4
// buffers, produced+consumed within one half-step (2 barriers / 4 rows).
// LDS = 4*134*(16+16+16+8) = 30016 B -> 5 blocks/CU, 10 waves/CU.

#define TPB   128
#define OUTW  116
#define SEGH  64
#define HW    1024
#define GW    134          // TPB + 6 guard cells for taps
#define EPSF  1e-6f
#define INV49 (1.0f/49.0f)

struct GFState {
    // raw ring: rows r-8..r-1 of (I,p0,p1,p2); slot = r&7
    float4 rr[8];
    // ab ring: ab rows produced at r-8..r-1; slot = r&7
    float ra0[8], rb0[8], ra1[8], rb1[8], ra2[8], rb2[8];
    // stage-1 vertical colsums (I, I*I, p, I*p) over raw rows y-6..y
    float sI, sII, sp0, sp1, sp2, sq0, sq1, sq2;
    // stage-2 vertical colsums over ab rows yc-6..yc
    float t6a0, t6b0, t6a1, t6b1, t6a2, t6b2;
    // prefetched raw rows for this half-step
    float4 cur[4];
};

template<int JB>
__device__ __forceinline__ void halfStep(
    GFState& S, int j0, int Yb, int x_in, bool xok, int xc, int tid,
    const float* __restrict__ Ip, const float* __restrict__ P0,
    const float* __restrict__ P1, const float* __restrict__ P2,
    float* __restrict__ Q0, float* __restrict__ Q1, float* __restrict__ Q2,
    float4 (*cs8A)[GW], float4 (*cs8B)[GW],
    float4 (*cs6A)[GW], float2 (*cs6B)[GW],
    bool dostore, bool dopref)
{
    // I at this half-step's output rows o = r-6: still in the raw ring
    // (slot (r-6)&7 = (JB+u+2)&7). Read BEFORE W8 evicts.
    float Io[4];
    #pragma unroll
    for (int u = 0; u < 4; ++u) Io[u] = S.rr[(JB+u+2)&7].x;

    // ---- W8: stage-1 vertical rolling colsums for rows r = j0..j0+3 -> LDS
    #pragma unroll
    for (int u = 0; u < 4; ++u) {
        const float4 c = S.cur[u];
        const float4 o = S.rr[(JB+u+1)&7];      // raw row r-7 (leaving)
        S.sI  += c.x - o.x;
        S.sII += c.x*c.x - o.x*o.x;
        S.sp0 += c.y - o.y;  S.sq0 += c.x*c.y - o.x*o.y;
        S.sp1 += c.z - o.z;  S.sq1 += c.x*c.z - o.x*o.z;
        S.sp2 += c.w - o.w;  S.sq2 += c.x*c.w - o.x*o.w;
        S.rr[(JB+u)&7] = c;
        cs8A[(JB+u)&3][tid+3] = make_float4(S.sI,  S.sII, S.sp0, S.sp1);
        cs8B[(JB+u)&3][tid+3] = make_float4(S.sp2, S.sq0, S.sq1, S.sq2);
    }
    // ---- barrier 1: cs8 writes visible (also protects prev half-step's
    // cs6 reads from this half-step's W6 writes below).
    __syncthreads();

    // ---- R8: horizontal 7-tap on cs8 -> ab row yc = y-3 -> stage-2
    //          vertical rolling colsums -> W6 to LDS
    #pragma unroll
    for (int u = 0; u < 4; ++u) {
        const int ls = (JB+u)&3;
        float4 A = make_float4(0.f,0.f,0.f,0.f);
        float4 B = make_float4(0.f,0.f,0.f,0.f);
        #pragma unroll
        for (int d = 0; d < 7; ++d) {
            float4 a = cs8A[ls][tid+d];
            float4 b = cs8B[ls][tid+d];
            A.x += a.x; A.y += a.y; A.z += a.z; A.w += a.w;
            B.x += b.x; B.y += b.y; B.z += b.z; B.w += b.w;
        }
        const int  yc   = Yb + j0 + u - 3;
        const bool abok = xok && ((unsigned)yc < HW);
        const float mi  = A.x*INV49, mii = A.y*INV49;
        const float rv  = __builtin_amdgcn_rcpf(mii - mi*mi + EPSF);
        float a0,b0,a1,b1,a2,b2, mp, mq, a, b;
        mp = A.z*INV49; mq = B.y*INV49;
        a = (mq - mi*mp)*rv; b = fmaf(-a, mi, mp);
        a0 = abok ? a : 0.f; b0 = abok ? b : 0.f;
        mp = A.w*INV49; mq = B.z*INV49;
        a = (mq - mi*mp)*rv; b = fmaf(-a, mi, mp);
        a1 = abok ? a : 0.f; b1 = abok ? b : 0.f;
        mp = B.x*INV49; mq = B.w*INV49;
        a = (mq - mi*mp)*rv; b = fmaf(-a, mi, mp);
        a2 = abok ? a : 0.f; b2 = abok ? b : 0.f;

        const int as = (JB+u)&7, al = (JB+u+1)&7;   // ab row r-7 leaves
        S.t6a0 += a0 - S.ra0[al]; S.ra0[as] = a0;
        S.t6b0 += b0 - S.rb0[al]; S.rb0[as] = b0;
        S.t6a1 += a1 - S.ra1[al]; S.ra1[as] = a1;
        S.t6b1 += b1 - S.rb1[al]; S.rb1[as] = b1;
        S.t6a2 += a2 - S.ra2[al]; S.ra2[as] = a2;
        S.t6b2 += b2 - S.rb2[al]; S.rb2[as] = b2;
        cs6A[ls][tid+3] = make_float4(S.t6a0, S.t6b0, S.t6a1, S.t6b1);
        cs6B[ls][tid+3] = make_float2(S.t6a2, S.t6b2);
    }
    // ---- barrier 2: cs6 writes visible (also protects this half-step's
    // cs8 reads from next half-step's W8 writes).
    __syncthreads();

    // ---- prefetch raw rows r = j0+4..j0+7 (consumed at next W8; latency
    // hidden under R6 taps + next W8 address math)
    if (dopref) {
        #pragma unroll
        for (int u = 0; u < 4; ++u) {
            const int y  = Yb + j0 + 4 + u;
            const bool ok = xok && ((unsigned)y < HW);
            const int yy = min(max(y, 0), HW-1);
            const size_t off = (size_t)yy*HW + xc;
            float v0 = Ip[off], v1 = P0[off], v2 = P1[off], v3 = P2[off];
            float4 v;
            v.x = ok ? v0 : 0.f; v.y = ok ? v1 : 0.f;
            v.z = ok ? v2 : 0.f; v.w = ok ? v3 : 0.f;
            S.cur[u] = v;
        }
    }

    // ---- R6: horizontal 7-tap on cs6 -> output rows o = r-6
    if (dostore) {
        const bool sok = (tid >= 6) && (tid < 122) && (x_in < HW);
        #pragma unroll
        for (int u = 0; u < 4; ++u) {
            const int ls = (JB+u)&3;
            float4 A6 = make_float4(0.f,0.f,0.f,0.f);
            float2 B6 = make_float2(0.f,0.f);
            #pragma unroll
            for (int d = 0; d < 7; ++d) {
                float4 a = cs6A[ls][tid+d];
                float2 b = cs6B[ls][tid+d];
                A6.x += a.x; A6.y += a.y; A6.z += a.z; A6.w += a.w;
                B6.x += b.x; B6.y += b.y;
            }
            const int o = Yb + j0 + u - 6;
            const size_t ooff = (size_t)o*HW + x_in;
            float q;
            q = fmaf(A6.x*INV49, Io[u], A6.y*INV49);
            q = fminf(fmaxf(q, 0.f), 1.f); if (sok) Q0[ooff] = q;
            q = fmaf(A6.z*INV49, Io[u], A6.w*INV49);
            q = fminf(fmaxf(q, 0.f), 1.f); if (sok) Q1[ooff] = q;
            q = fmaf(B6.x*INV49, Io[u], B6.y*INV49);
            q = fminf(fmaxf(q, 0.f), 1.f); if (sok) Q2[ooff] = q;
        }
    }
}

__global__ __launch_bounds__(TPB, 2) void gf_kernel(
    const float* __restrict__ I, const float* __restrict__ P,
    float* __restrict__ Q)
{
    __shared__ float4 cs8A[4][GW];   // 8576 B: sI,sII,sp0,sp1
    __shared__ float4 cs8B[4][GW];   // 8576 B: sp2,sq0,sq1,sq2
    __shared__ float4 cs6A[4][GW];   // 8576 B: t6a0,t6b0,t6a1,t6b1
    __shared__ float2 cs6B[4][GW];   // 4288 B: t6a2,t6b2   -> 30016 B total

    const int s   = blockIdx.x;      // x-stripe (9)
    const int seg = blockIdx.y;      // y-segment (16)
    const int b   = blockIdx.z;      // batch (8)
    const int tid = threadIdx.x;

    const int X0   = s*OUTW - 6;
    const int Yb   = seg*SEGH - 6;   // image row of sweep r=0
    const int x_in = X0 + tid;
    const bool xok = (unsigned)x_in < HW;
    const int  xc  = min(max(x_in, 0), HW-1);

    const float* Ip = I + (size_t)b*HW*HW;
    const float* P0 = P + ((size_t)b*3 + 0)*HW*HW;
    const float* P1 = P + ((size_t)b*3 + 1)*HW*HW;
    const float* P2 = P + ((size_t)b*3 + 2)*HW*HW;
    float* Q0 = Q + ((size_t)b*3 + 0)*HW*HW;
    float* Q1 = Q + ((size_t)b*3 + 1)*HW*HW;
    float* Q2 = Q + ((size_t)b*3 + 2)*HW*HW;

    // Zero-init LDS once: interior cells are rewritten every half-step, but
    // the 2x3 guard columns per slot are read by edge threads and must be
    // finite (edge-thread results are never stored, but keep them clean).
    {
        float4* zA = (float4*)cs8A;
        float4* zB = (float4*)cs8B;
        float4* zC = (float4*)cs6A;
        float2* zD = (float2*)cs6B;
        const float4 z4 = make_float4(0.f,0.f,0.f,0.f);
        const float2 z2 = make_float2(0.f,0.f);
        for (int i = tid; i < 4*GW; i += TPB) {
            zA[i] = z4; zB[i] = z4; zC[i] = z4; zD[i] = z2;
        }
    }

    GFState S;
    S.sI=S.sII=S.sp0=S.sp1=S.sp2=S.sq0=S.sq1=S.sq2=0.f;
    S.t6a0=S.t6b0=S.t6a1=S.t6b1=S.t6a2=S.t6b2=0.f;
    #pragma unroll
    for (int i = 0; i < 8; ++i) {
        S.rr[i] = make_float4(0.f,0.f,0.f,0.f);
        S.ra0[i]=S.rb0[i]=S.ra1[i]=S.rb1[i]=S.ra2[i]=S.rb2[i]=0.f;
    }
    // preload raw rows r = 0..3
    #pragma unroll
    for (int u = 0; u < 4; ++u) {
        const int y = Yb + u;
        const bool ok = xok && ((unsigned)y < HW);
        const int yy = min(max(y, 0), HW-1);
        const size_t off = (size_t)yy*HW + xc;
        float v0 = Ip[off], v1 = P0[off], v2 = P1[off], v3 = P2[off];
        float4 v;
        v.x = ok ? v0 : 0.f; v.y = ok ? v1 : 0.f;
        v.z = ok ? v2 : 0.f; v.w = ok ? v3 : 0.f;
        S.cur[u] = v;
    }

    __syncthreads();   // LDS zero-init visible before first taps

    // 19 half-steps: r = 0..75 (output rows o = Yb+r-6 valid for r>=12)
    for (int m = 0; m < 9; ++m) {
        const int j0 = m*8;
        halfStep<0>(S, j0,   Yb, x_in, xok, xc, tid, Ip, P0, P1, P2,
                    Q0, Q1, Q2, cs8A, cs8B, cs6A, cs6B,
                    (j0   >= 12), true);
        halfStep<4>(S, j0+4, Yb, x_in, xok, xc, tid, Ip, P0, P1, P2,
                    Q0, Q1, Q2, cs8A, cs8B, cs6A, cs6B,
                    (j0+4 >= 12), true);
    }
    halfStep<0>(S, 72, Yb, x_in, xok, xc, tid, Ip, P0, P1, P2,
                Q0, Q1, Q2, cs8A, cs8B, cs6A, cs6B,
                true, false);
}

extern "C" void kernel_launch(void* const* d_in, const int* in_sizes, int n_in,
                              void* d_out, int out_size, void* d_ws, size_t ws_size,
                              hipStream_t stream) {
    const float* I = (const float*)d_in[0];
    const float* P = (const float*)d_in[1];
    // d_in[2] = radius (always 3; hardcoded)
    float* Q = (float*)d_out;

    dim3 grid(9, 16, 8);   // x-stripes, y-segments, batch
    gf_kernel<<<grid, TPB, 0, stream>>>(I, P, Q);
}